// Round 5
// baseline (263.848 us; speedup 1.0000x reference)
//
#include <hip/hip_runtime.h>
#include <stdint.h>

#define BATCH 16
#define CIN   32
#define HH    128
#define WW    128
#define BO    32
#define OCH   128   // 4*BO
#define NCH   16    // h-chunks (8 rows each)
#define NW    8     // waves per block == rows per chunk
#define DEPTH 64    // handoff ring depth (power of 2)

// ws: [0,4096) progress ints
//     [4096, +RINGSZ) tagged handoff ring
//     [4096+RINGSZ, +I2SSZ) i2s buffer (fp32) -- only if ws_size permits
#define RINGSZ ((size_t)BATCH * NCH * DEPTH * BO * 8)
#define I2SSZ  ((size_t)BATCH * HH * WW * OCH * 4)

// ============================ main kernel (R5) ============================
__global__ __launch_bounds__(512, 2) void diag_lstm_scan_v5(
    const float* __restrict__ x, const float* __restrict__ W2g,
    const float* __restrict__ b2, const float* __restrict__ W1g,
    const float* __restrict__ b1, float* __restrict__ out,
    int* __restrict__ progress, unsigned long long* __restrict__ hand,
    float* __restrict__ i2s)
{
    const int tid = threadIdx.x;
    const int l   = tid & 63;           // lane
    const int w   = tid >> 6;           // wave id == local row
    const int blk = blockIdx.x;
    const int b = (blk & 7) + ((blk >> 7) << 3);   // XCD-affinity remap
    const int k = (blk >> 3) & (NCH - 1);
    const int row = k * NW + w;

    __shared__ __attribute__((aligned(16))) float phs[2][NW + 1][BO];
    __shared__ __attribute__((aligned(16))) float xtile[NW][CIN][32];
    __shared__ __attribute__((aligned(16))) float gbuf[NW][OCH];

    for (int i = tid; i < 2 * (NW + 1) * BO; i += 512) ((float*)phs)[i] = 0.f;

    const int o0 = 2 * l, o1 = 2 * l + 1;
    float* myi2s = i2s + (size_t)(b * HH + row) * WW * OCH;

    // ---------------- pre-phase: i2s for own row (not on the chain) --------
    {
        float w2a_[CIN], w2b_[CIN];
#pragma unroll
        for (int c = 0; c < CIN; ++c) {
            w2a_[c] = W2g[o0 * CIN + c];
            w2b_[c] = W2g[o1 * CIN + c];
        }
        const float biasA = b2[o0] + b1[o0];
        const float biasB = b2[o1] + b1[o1];

        for (int t0 = 0; t0 < WW; t0 += 32) {
            // stage x tile for own row: xtile[w][c][i] = x[b,c,row,t0+i-row]
#pragma unroll
            for (int it = 0; it < 16; ++it) {
                const int idx = it * 64 + l;
                const int c = idx >> 5, i = idx & 31;
                const int wp = t0 + i - row;
                xtile[w][c][i] = (wp >= 0)
                    ? x[((size_t)(b * CIN + c) * HH + row) * WW + wp] : 0.f;
            }
            asm volatile("s_waitcnt lgkmcnt(0)" ::: "memory");

            float accA[32], accB[32];
#pragma unroll
            for (int i = 0; i < 32; ++i) { accA[i] = biasA; accB[i] = biasB; }
#pragma unroll
            for (int c = 0; c < CIN; ++c) {
                const float4* xq = (const float4*)&xtile[w][c][0];
#pragma unroll
                for (int q = 0; q < 8; ++q) {
                    const float4 xv = xq[q];
                    accA[4*q+0] = fmaf(w2a_[c], xv.x, accA[4*q+0]);
                    accB[4*q+0] = fmaf(w2b_[c], xv.x, accB[4*q+0]);
                    accA[4*q+1] = fmaf(w2a_[c], xv.y, accA[4*q+1]);
                    accB[4*q+1] = fmaf(w2b_[c], xv.y, accB[4*q+1]);
                    accA[4*q+2] = fmaf(w2a_[c], xv.z, accA[4*q+2]);
                    accB[4*q+2] = fmaf(w2b_[c], xv.z, accB[4*q+2]);
                    accA[4*q+3] = fmaf(w2a_[c], xv.w, accA[4*q+3]);
                    accB[4*q+3] = fmaf(w2b_[c], xv.w, accB[4*q+3]);
                }
            }
#pragma unroll
            for (int i = 0; i < 32; ++i) {
                *(float2*)&myi2s[(size_t)(t0 + i) * OCH + o0] =
                    make_float2(accA[i], accB[i]);
            }
            __syncthreads();   // xtile reuse across t0 tiles
        }
    }
    asm volatile("s_waitcnt vmcnt(0)" ::: "memory");  // i2s stores visible to own loads
    __syncthreads();

    // ---------------- load + pin recurrent weights (128 VGPRs) -------------
    float w1pa[CIN], w1ca[CIN], w1pb[CIN], w1cb[CIN];
#pragma unroll
    for (int c = 0; c < CIN; ++c) {
        w1pa[c] = W1g[(o0 * CIN + c) * 2 + 0];
        w1ca[c] = W1g[(o0 * CIN + c) * 2 + 1];
        w1pb[c] = W1g[(o1 * CIN + c) * 2 + 0];
        w1cb[c] = W1g[(o1 * CIN + c) * 2 + 1];
    }
#pragma unroll
    for (int c = 0; c < CIN; ++c) {
        asm volatile("" : "+v"(w1pa[c]), "+v"(w1ca[c]),
                          "+v"(w1pb[c]), "+v"(w1cb[c]));
    }

    // cell role
    const int j = l & 31;
    float pc = 0.f, ob0 = 0.f, ob1 = 0.f, ob2 = 0.f;
    float* outrow = out + ((size_t)(b * BO + j) * HH + row) * WW;

    const int kprev = (k > 0) ? k - 1 : 0;
    const unsigned long long* srcbase =
        hand + (size_t)((b * NCH + kprev) * DEPTH) * BO + j;
    unsigned long long* dstbase =
        hand + (size_t)((b * NCH + k) * DEPTH) * BO + j;
    int* myprog   = progress + (b * NCH + k);
    int* consprog = progress + (b * NCH + k) + 1;

    unsigned long long pre = 0ull;
    const float2* myi2s2 = (const float2*)myi2s;   // float2 idx = t*64 + l
    float2 ipre = myi2s2[l];                        // t = 0

    __syncthreads();

    // ---------------- scan ----------------
    for (int t = 0; t < WW; ++t) {
        const int par = t & 1;

        const float2 icur = ipre;
        const int tn = (t + 1 < WW) ? t + 1 : WW - 1;
        ipre = myi2s2[(size_t)tn * 64 + l];

        // boundary poll (wave 0; value tagged t lives at slot (t-1)&63)
        if (w == 0 && k > 0) {
            if (t > 0) {
                unsigned long long q = pre;
                while (__any((unsigned)(q >> 32) != (unsigned)t)) {
                    q = __hip_atomic_load(&srcbase[(size_t)((t - 1) & (DEPTH - 1)) * BO],
                                          __ATOMIC_RELAXED, __HIP_MEMORY_SCOPE_AGENT);
                }
                if (l < 32) phs[par][0][l] = __uint_as_float((unsigned)q);
            }
            pre = __hip_atomic_load(&srcbase[(size_t)(t & (DEPTH - 1)) * BO],
                                    __ATOMIC_RELAXED, __HIP_MEMORY_SCOPE_AGENT);
        }
        asm volatile("s_waitcnt lgkmcnt(0)" ::: "memory");

        // gates: 2 channels/lane, recurrent part only
        float ga = icur.x, gb = icur.y;
        {
            const float4* pv4 = (const float4*)(&phs[par][w][0]);      // h(row-1)
            const float4* qv4 = (const float4*)(&phs[par][w + 1][0]);  // h(row)
#pragma unroll
            for (int cc = 0; cc < CIN / 4; ++cc) {
                const float4 pv = pv4[cc];
                const float4 qv = qv4[cc];
                const float* ps = (const float*)&pv;
                const float* qs = (const float*)&qv;
#pragma unroll
                for (int ci = 0; ci < 4; ++ci) {
                    const int c = 4 * cc + ci;
                    ga = fmaf(w1pa[c], ps[ci], ga);
                    gb = fmaf(w1pb[c], ps[ci], gb);
                    ga = fmaf(w1ca[c], qs[ci], ga);
                    gb = fmaf(w1cb[c], qs[ci], gb);
                }
            }
        }
        *(float2*)&gbuf[w][o0] = make_float2(ga, gb);
        asm volatile("s_waitcnt lgkmcnt(0)" ::: "memory");

        // cell update (lanes < 32), wave-private
        if (l < 32) {
            if (w == NW - 1 && k < NCH - 1 && (t & 15) == 0 && t >= 48) {
                while (__hip_atomic_load(consprog, __ATOMIC_RELAXED,
                                         __HIP_MEMORY_SCOPE_AGENT) < t - 47) { }
            }
            const float go = gbuf[w][l];
            const float gf = gbuf[w][32 + l];
            const float gi = gbuf[w][64 + l];
            const float gg = gbuf[w][96 + l];
            const float so = 1.f / (1.f + __expf(-go));
            const float sf = 1.f / (1.f + __expf(-gf));
            const float si = 1.f / (1.f + __expf(-gi));
            const float tg = 2.f / (1.f + __expf(-2.f * gg)) - 1.f;
            const float nc = sf * pc + si * tg;
            const float th = 2.f / (1.f + __expf(-2.f * nc)) - 1.f;
            const float nh = so * th;
            pc = nc;
            phs[par ^ 1][w + 1][l] = nh;

            const int ph4 = t & 3;
            if (ph4 == 0) ob0 = nh;
            else if (ph4 == 1) ob1 = nh;
            else if (ph4 == 2) ob2 = nh;
            else *(float4*)(outrow + (t - 3)) = make_float4(ob0, ob1, ob2, nh);

            if (w == NW - 1 && k < NCH - 1) {
                unsigned long long q = ((unsigned long long)(unsigned)(t + 1) << 32)
                                     | (unsigned long long)__float_as_uint(nh);
                __hip_atomic_store(&dstbase[(size_t)(t & (DEPTH - 1)) * BO], q,
                                   __ATOMIC_RELAXED, __HIP_MEMORY_SCOPE_AGENT);
            }
            if (w == 0 && l == 0) {
                __hip_atomic_store(myprog, t + 1, __ATOMIC_RELAXED,
                                   __HIP_MEMORY_SCOPE_AGENT);
            }
        }
        __syncthreads();
    }
}

// ===================== fallback (R4, proven, ws-lean) =====================
__global__ __launch_bounds__(512, 2) void diag_lstm_scan_v4(
    const float* __restrict__ x, const float* __restrict__ W2g,
    const float* __restrict__ b2, const float* __restrict__ W1g,
    const float* __restrict__ b1, float* __restrict__ out,
    int* __restrict__ progress, unsigned long long* __restrict__ hand)
{
    const int tid = threadIdx.x;
    const int l   = tid & 63;
    const int w   = tid >> 6;
    const int blk = blockIdx.x;
    const int b = (blk & 7) + ((blk >> 7) << 3);
    const int k = (blk >> 3) & (NCH - 1);
    const int row = k * NW + w;

    __shared__ __attribute__((aligned(16))) float phs[2][NW + 1][BO];
    __shared__ __attribute__((aligned(16))) float xbuf[NW][CIN];
    __shared__ __attribute__((aligned(16))) float gbuf[NW][OCH];

    for (int i = tid; i < 2 * (NW + 1) * BO; i += 512) ((float*)phs)[i] = 0.f;

    const int o0 = 2 * l, o1 = 2 * l + 1;
    float w2a[CIN], w2b[CIN], w1pa[CIN], w1ca[CIN], w1pb[CIN], w1cb[CIN];
#pragma unroll
    for (int c = 0; c < CIN; ++c) {
        w2a[c]  = W2g[o0 * CIN + c];
        w2b[c]  = W2g[o1 * CIN + c];
        w1pa[c] = W1g[(o0 * CIN + c) * 2 + 0];
        w1ca[c] = W1g[(o0 * CIN + c) * 2 + 1];
        w1pb[c] = W1g[(o1 * CIN + c) * 2 + 0];
        w1cb[c] = W1g[(o1 * CIN + c) * 2 + 1];
    }
    const float biasA = b2[o0] + b1[o0];
    const float biasB = b2[o1] + b1[o1];

    const int j = l & 31;
    float pc = 0.f, ob0 = 0.f, ob1 = 0.f, ob2 = 0.f;
    float* outrow = out + ((size_t)(b * BO + j) * HH + row) * WW;

    const int kprev = (k > 0) ? k - 1 : 0;
    const unsigned long long* srcbase =
        hand + (size_t)((b * NCH + kprev) * DEPTH) * BO + j;
    unsigned long long* dstbase =
        hand + (size_t)((b * NCH + k) * DEPTH) * BO + j;
    int* myprog   = progress + (b * NCH + k);
    int* consprog = progress + (b * NCH + k) + 1;

    unsigned long long pre = 0ull;
    __syncthreads();

    for (int t = 0; t < WW; ++t) {
        const int par = t & 1;
        if (l < 32) {
            const int wp = t - row;
            xbuf[w][l] = (wp >= 0)
                ? x[((size_t)(b * CIN + l) * HH + row) * WW + wp] : 0.f;
        }
        if (w == 0 && k > 0) {
            if (t > 0) {
                unsigned long long q = pre;
                while (__any((unsigned)(q >> 32) != (unsigned)t)) {
                    q = __hip_atomic_load(&srcbase[(size_t)((t - 1) & (DEPTH - 1)) * BO],
                                          __ATOMIC_RELAXED, __HIP_MEMORY_SCOPE_AGENT);
                }
                if (l < 32) phs[par][0][l] = __uint_as_float((unsigned)q);
            }
            pre = __hip_atomic_load(&srcbase[(size_t)(t & (DEPTH - 1)) * BO],
                                    __ATOMIC_RELAXED, __HIP_MEMORY_SCOPE_AGENT);
        }
        asm volatile("s_waitcnt lgkmcnt(0)" ::: "memory");

        float ga = biasA, gb = biasB;
        {
            const float4* xb4 = (const float4*)(&xbuf[w][0]);
            const float4* pv4 = (const float4*)(&phs[par][w][0]);
            const float4* qv4 = (const float4*)(&phs[par][w + 1][0]);
#pragma unroll
            for (int cc = 0; cc < CIN / 4; ++cc) {
                const float4 xv = xb4[cc];
                const float4 pv = pv4[cc];
                const float4 qv = qv4[cc];
                const float* xs = (const float*)&xv;
                const float* ps = (const float*)&pv;
                const float* qs = (const float*)&qv;
#pragma unroll
                for (int ci = 0; ci < 4; ++ci) {
                    const int c = 4 * cc + ci;
                    ga = fmaf(w2a[c],  xs[ci], ga);
                    gb = fmaf(w2b[c],  xs[ci], gb);
                    ga = fmaf(w1pa[c], ps[ci], ga);
                    gb = fmaf(w1pb[c], ps[ci], gb);
                    ga = fmaf(w1ca[c], qs[ci], ga);
                    gb = fmaf(w1cb[c], qs[ci], gb);
                }
            }
        }
        *(float2*)&gbuf[w][o0] = make_float2(ga, gb);
        asm volatile("s_waitcnt lgkmcnt(0)" ::: "memory");

        if (l < 32) {
            if (w == NW - 1 && k < NCH - 1 && (t & 15) == 0 && t >= 48) {
                while (__hip_atomic_load(consprog, __ATOMIC_RELAXED,
                                         __HIP_MEMORY_SCOPE_AGENT) < t - 47) { }
            }
            const float go = gbuf[w][l];
            const float gf = gbuf[w][32 + l];
            const float gi = gbuf[w][64 + l];
            const float gg = gbuf[w][96 + l];
            const float so = 1.f / (1.f + __expf(-go));
            const float sf = 1.f / (1.f + __expf(-gf));
            const float si = 1.f / (1.f + __expf(-gi));
            const float tg = 2.f / (1.f + __expf(-2.f * gg)) - 1.f;
            const float nc = sf * pc + si * tg;
            const float th = 2.f / (1.f + __expf(-2.f * nc)) - 1.f;
            const float nh = so * th;
            pc = nc;
            phs[par ^ 1][w + 1][l] = nh;

            const int ph4 = t & 3;
            if (ph4 == 0) ob0 = nh;
            else if (ph4 == 1) ob1 = nh;
            else if (ph4 == 2) ob2 = nh;
            else *(float4*)(outrow + (t - 3)) = make_float4(ob0, ob1, ob2, nh);

            if (w == NW - 1 && k < NCH - 1) {
                unsigned long long q = ((unsigned long long)(unsigned)(t + 1) << 32)
                                     | (unsigned long long)__float_as_uint(nh);
                __hip_atomic_store(&dstbase[(size_t)(t & (DEPTH - 1)) * BO], q,
                                   __ATOMIC_RELAXED, __HIP_MEMORY_SCOPE_AGENT);
            }
            if (w == 0 && l == 0) {
                __hip_atomic_store(myprog, t + 1, __ATOMIC_RELAXED,
                                   __HIP_MEMORY_SCOPE_AGENT);
            }
        }
        __syncthreads();
    }
}

extern "C" void kernel_launch(void* const* d_in, const int* in_sizes, int n_in,
                              void* d_out, int out_size, void* d_ws, size_t ws_size,
                              hipStream_t stream) {
    const float* x  = (const float*)d_in[0];
    const float* W2 = (const float*)d_in[1];
    const float* b2 = (const float*)d_in[2];
    const float* W1 = (const float*)d_in[3];
    const float* b1 = (const float*)d_in[4];
    float* out = (float*)d_out;

    int* progress = (int*)d_ws;
    unsigned long long* hand = (unsigned long long*)((char*)d_ws + 4096);
    float* i2s = (float*)((char*)d_ws + 4096 + RINGSZ);

    const size_t need = 4096 + RINGSZ + I2SSZ;

    // clear progress + ring tags (stale tags alias valid ones across replays)
    hipMemsetAsync(d_ws, 0, 4096 + RINGSZ, stream);

    dim3 grid(BATCH * NCH), block(512);
    if (ws_size >= need) {
        hipLaunchKernelGGL(diag_lstm_scan_v5, grid, block, 0, stream,
                           x, W2, b2, W1, b1, out, progress, hand, i2s);
    } else {
        hipLaunchKernelGGL(diag_lstm_scan_v4, grid, block, 0, stream,
                           x, W2, b2, W1, b1, out, progress, hand);
    }
}